// Round 1
// baseline (10.438 us; speedup 1.0000x reference)
//
#include <hip/hip_runtime.h>

// SimpleSpectralConv2D: 3x3 VALID conv with position-modulated weights.
// out[f,r,co,c] = relu( sum_{b,j} SMk[f,3b+j] * (Li[(r+b)*64+co+j] - Lo[r*62+co])
//                                  * x[r+b, co+j, c] )
// Shapes: x[64,64,64] f32, SMk[8,9], Li[4096], Lo[3844], out[8,62,62,64].

#define OUTW 62
#define OUTH 62
#define NPIX (OUTH * OUTW)   // 3844
#define NC   64
#define NF   8

__global__ __launch_bounds__(256) void spectral_conv_kernel(
    const float* __restrict__ x,    // [64*64, 64]
    const float* __restrict__ smk,  // [8, 9]
    const float* __restrict__ li,   // [4096]
    const float* __restrict__ lo,   // [3844]
    float* __restrict__ out)        // [8, 3844, 64]
{
    __shared__ float s_smk[NF * 9 + 8];   // 72 + pad
    int tid = threadIdx.x;
    if (tid < NF * 9) s_smk[tid] = smk[tid];
    __syncthreads();

    int c      = tid & 63;                 // channel
    int plocal = tid >> 6;                 // 0..3
    int pix    = blockIdx.x * 4 + plocal;  // 3844 = 961*4, exact
    int r  = pix / OUTW;                   // const divide -> magic mul
    int co = pix - r * OUTW;

    float lov = lo[pix];

    float acc[NF];
    #pragma unroll
    for (int f = 0; f < NF; ++f) acc[f] = 0.f;

    #pragma unroll
    for (int b = 0; b < 3; ++b) {
        #pragma unroll
        for (int j = 0; j < 3; ++j) {
            int col  = (b + r) * 64 + co + j;      // input row/col flat index
            float xv = x[col * NC + c];            // coalesced over c
            float t  = (li[col] - lov) * xv;       // wave-uniform li load
            int tap  = b * 3 + j;
            #pragma unroll
            for (int f = 0; f < NF; ++f)
                acc[f] = fmaf(s_smk[f * 9 + tap], t, acc[f]);
        }
    }

    #pragma unroll
    for (int f = 0; f < NF; ++f)
        out[f * (NPIX * NC) + pix * NC + c] = fmaxf(acc[f], 0.f);
}

extern "C" void kernel_launch(void* const* d_in, const int* in_sizes, int n_in,
                              void* d_out, int out_size, void* d_ws, size_t ws_size,
                              hipStream_t stream) {
    const float* x   = (const float*)d_in[0];  // (1,64,64,64)
    const float* smk = (const float*)d_in[1];  // (8,9)
    const float* li  = (const float*)d_in[2];  // (1,4096)
    const float* lo  = (const float*)d_in[3];  // (3844,1)
    float* out = (float*)d_out;                // (8,62,62,64)

    dim3 grid(NPIX / 4);   // 961 blocks, 4 pixels each
    dim3 block(256);
    spectral_conv_kernel<<<grid, block, 0, stream>>>(x, smk, li, lo, out);
}